// Round 6
// baseline (235.591 us; speedup 1.0000x reference)
//
#include <hip/hip_runtime.h>

typedef unsigned int u32;
typedef unsigned long long u64;
typedef float v2f __attribute__((ext_vector_type(2)));

#define NBATCH 8
#define NPTS   4096
#define NQTOT  (NBATCH * NPTS)   /* 32768 */
#define KNN    16
#define NBASIS 8
#define OUTM   64
#define NSPLIT 8
#define WIN    (NPTS / NSPLIT)   /* 512 candidates per window */
#define QPB    64
#define TKNN   (QPB * NSPLIT)    /* 512 threads = 8 waves */
#define CAP    16
#define GRP    8

// sentinel: d2 = +inf, idx = all-ones (sorts last)
#define SENT 0x7f800000ffffffffull

__device__ __forceinline__ void ce(u64& x, u64& y) {
  u64 a = x, b = y;
  bool sw = b < a;
  x = sw ? b : a;
  y = sw ? a : b;
}

// Batcher odd-even mergesort network (fully unrolled).
template <int N>
__device__ __forceinline__ void oems_sort(u64* a) {
#pragma unroll
  for (int p = 1; p < N; p <<= 1) {
#pragma unroll
    for (int k = p; k >= 1; k >>= 1) {
#pragma unroll
      for (int j = k & (p - 1); j + k < N; j += 2 * k) {
#pragma unroll
        for (int i = 0; i < k; ++i) {
          int lo = i + j, hi = i + j + k;
          if (hi < N && (lo / (2 * p)) == (hi / (2 * p)))
            ce(a[lo], a[hi]);
        }
      }
    }
  }
}

// t, a sorted asc -> t = smallest 16 of union, sorted asc.
__device__ __forceinline__ void merge16(u64 t[16], const u64 a[16]) {
  u64 m[16];
#pragma unroll
  for (int i = 0; i < 16; ++i) {
    u64 x = t[i], y = a[15 - i];
    m[i] = (x < y) ? x : y;
  }
#pragma unroll
  for (int k = 8; k >= 1; k >>= 1) {
#pragma unroll
    for (int i = 0; i < 16; ++i) {
      if ((i & k) == 0) ce(m[i], m[i | k]);
    }
  }
#pragma unroll
  for (int i = 0; i < 16; ++i) t[i] = m[i];
}

// Bit-exact d2 for a candidate pair: ((dx^2+dy^2)+dz^2), no FMA contraction.
// float2 ext-vector ops lower to v_pk_{add,mul}_f32 (IEEE-identical rounding).
__device__ __forceinline__ v2f d2pair(v2f cx, v2f cy, v2f cz, v2f qx, v2f qy,
                                      v2f qz) {
#pragma clang fp contract(off)
  v2f dx = cx - qx;
  v2f dy = cy - qy;
  v2f dz = cz - qz;
  v2f d2 = (dx * dx + dy * dy) + dz * dz;
  return d2;
}

// Flush per-thread LDS append buffer into register top-16; tighten shared thr.
__device__ __forceinline__ void flush_buf(u64* col, int& c, u64 t16[16],
                                          u32* sThrU, int ql) {
  u64 a[16];
#pragma unroll
  for (int e = 0; e < 16; ++e) a[e] = (e < c) ? col[(size_t)e * TKNN] : SENT;
  oems_sort<16>(a);
  merge16(t16, a);
  c = 0;
  atomicMin(&sThrU[ql], (u32)(t16[15] >> 32));
}

// Fused kNN + tensor-product features.
// Block = 64 queries x 8 disjoint candidate windows (512 thr). Each thread
// keeps the exact top-16 of its (query, window) stream in registers, pruned
// by a shared per-query threshold (atomicMin of every contributor's local
// 16th-best — always a valid upper bound on the global 16th). Tree-merge of
// the 8 lists via LDS (3 rounds) -> exact global top-16. Epilogue: owner
// computes M[8][3]; all waves do the W-contraction with lane = w.
__global__ __launch_bounds__(TKNN) void se3_kernel(
    const float* __restrict__ Xp, const float* __restrict__ Yp,
    const float* __restrict__ Zp, const float4* __restrict__ cpad,
    const float* __restrict__ Wmat, float* __restrict__ out) {
  __shared__ u64 sBuf[CAP * TKNN];  // 64 KB columns; reused as merge staging
  __shared__ u32 sThrU[QPB];
  __shared__ float sM[QPB * 25];    // M[8][3] per query, stride 25

  const int b = blockIdx.x;
  const int qg = blockIdx.y;
  const int tid = threadIdx.x;
  const int ql = tid & 63;
  const int sp = tid >> 6;  // window id, wave-uniform
  const int qi = qg * QPB + ql;
  const int base = b * NPTS;

  if (tid < QPB) sThrU[tid] = 0x7f800000u;  // +inf

  // per-lane query coords (coalesced)
  const float qx = Xp[base + qi];
  const float qy = Yp[base + qi];
  const float qz = Zp[base + qi];
  const v2f qxx = {qx, qx}, qyy = {qy, qy}, qzz = {qz, qz};

  // wave-uniform candidate window -> scalar loads feeding packed math
  const int wbase = __builtin_amdgcn_readfirstlane(sp * WIN);
  const v2f* xs2 = (const v2f*)(Xp + base + wbase);
  const v2f* ys2 = (const v2f*)(Yp + base + wbase);
  const v2f* zs2 = (const v2f*)(Zp + base + wbase);

  __syncthreads();  // sThrU init visible

  // ---- Seed: exact sorted top-16 of this window's first 16 candidates ----
  u64 t16[16];
  {
    float cd[16];
#pragma unroll
    for (int p = 0; p < 8; ++p) {
      v2f d2 = d2pair(xs2[p], ys2[p], zs2[p], qxx, qyy, qzz);
      cd[2 * p + 0] = d2.x;
      cd[2 * p + 1] = d2.y;
    }
#pragma unroll
    for (int i = 0; i < 16; ++i) {
      u64 v = ((u64)__float_as_uint(cd[i]) << 32) | (u32)(wbase + i);
      t16[i] = (wbase + i == qi) ? SENT : v;
    }
    oems_sort<16>(t16);
    atomicMin(&sThrU[ql], (u32)(t16[15] >> 32));
  }
  __syncthreads();  // all seeds folded into shared thresholds

  volatile u32* vThr = sThrU;  // defeat hoisting: other threads atomicMin this
  int c = 0;
  u64* col = sBuf + tid;

  // ---- Main scan: candidates [16, WIN) in groups of 8 (4 packed pairs) ----
  for (int g = 16; g < WIN; g += GRP) {
    v2f d2p[4];
#pragma unroll
    for (int p = 0; p < 4; ++p)
      d2p[p] = d2pair(xs2[(g >> 1) + p], ys2[(g >> 1) + p], zs2[(g >> 1) + p],
                      qxx, qyy, qzz);
    const float thr = __uint_as_float(vThr[ql]);
    int want = 0;
#pragma unroll
    for (int i = 0; i < GRP; ++i)
      want |= (d2p[i >> 1][i & 1] <= thr) ? (1 << i) : 0;
    if (__any(want)) {
      if (__any(c > CAP - GRP)) flush_buf(col, c, t16, sThrU, ql);
#pragma unroll
      for (int i = 0; i < GRP; ++i) {
        if (want & (1 << i)) {
          int j = wbase + g + i;
          if (j != qi) {  // self always passes thr; exclude on rare path
            col[(size_t)c * TKNN] =
                ((u64)__float_as_uint(d2p[i >> 1][i & 1]) << 32) | (u32)j;
            c++;
          }
        }
      }
    }
  }
  flush_buf(col, c, t16, sThrU, ql);

  // ---- Tree merge of the 8 window lists (3 LDS rounds) ----
  __syncthreads();  // column buffers dead; reuse sBuf as staging
  u64* stage = sBuf;  // layout [src][ql][17]
#pragma unroll
  for (int h = 4; h >= 1; h >>= 1) {
    if (sp >= h && sp < 2 * h) {
#pragma unroll
      for (int e = 0; e < 16; ++e)
        stage[(size_t)((sp - h) * QPB + ql) * 17 + e] = t16[e];
    }
    __syncthreads();
    if (sp < h) {
      u64 a[16];
#pragma unroll
      for (int e = 0; e < 16; ++e)
        a[e] = stage[(size_t)(sp * QPB + ql) * 17 + e];
      merge16(t16, a);
    }
    __syncthreads();
  }

  // ---- Epilogue phase 1 (owner wave): M[8][3] from exact top-16 ----
  if (sp == 0) {
    float M[24];
#pragma unroll
    for (int j = 0; j < 24; ++j) M[j] = 0.f;
#pragma unroll
    for (int chk = 0; chk < 4; ++chk) {
      float4 nc[4];
      float dd[4];
#pragma unroll
      for (int e = 0; e < 4; ++e) {
        u64 v = t16[chk * 4 + e];
        nc[e] = cpad[base + (int)(u32)v];  // independent gathers
        dd[e] = __uint_as_float((u32)(v >> 32));
      }
#pragma unroll
      for (int e = 0; e < 4; ++e) {
        float rx = nc[e].x - qx;  // sender - receiver
        float ry = nc[e].y - qy;
        float rz = nc[e].z - qz;
        float dist = sqrtf(dd[e]);
        float inv = 1.0f / (dist + 1e-8f);
        rx *= inv; ry *= inv; rz *= inv;
        float cut = fminf(dist * 0.1f, 1.0f);
        float g[NBASIS], s = 0.f;
#pragma unroll
        for (int v = 0; v < NBASIS; ++v) {
          float t = cut - (float)v * (1.0f / 7.0f);
          g[v] = __expf(-32.0f * t * t);  // sigma = 1/8 -> 1/(2s^2) = 32
          s += g[v];
        }
        float rs = 1.0f / s;
#pragma unroll
        for (int v = 0; v < NBASIS; ++v) {
          float rb = g[v] * rs;
          M[v * 3 + 0] = fmaf(rb, rx, M[v * 3 + 0]);
          M[v * 3 + 1] = fmaf(rb, ry, M[v * 3 + 1]);
          M[v * 3 + 2] = fmaf(rb, rz, M[v * 3 + 2]);
        }
      }
    }
#pragma unroll
    for (int j = 0; j < 24; ++j) sM[ql * 25 + j] = M[j];
  }
  __syncthreads();

  // ---- Epilogue phase 2 (all waves): out[q][w*3+m], lane w = ql ----
  float wreg[NBASIS];
#pragma unroll
  for (int v = 0; v < NBASIS; ++v) wreg[v] = Wmat[v * OUTM + ql];
  const float scale = 0.022097086912079608f;  // (1/sqrt(8)) / 16
#pragma unroll
  for (int i = 0; i < 8; ++i) {
    int q = sp * 8 + i;  // wave-uniform -> sM broadcasts
    const float* mq = sM + q * 25;
    float a0 = 0.f, a1 = 0.f, a2 = 0.f;
#pragma unroll
    for (int v = 0; v < NBASIS; ++v) {
      a0 = fmaf(wreg[v], mq[v * 3 + 0], a0);
      a1 = fmaf(wreg[v], mq[v * 3 + 1], a1);
      a2 = fmaf(wreg[v], mq[v * 3 + 2], a2);
    }
    size_t o = (size_t)(base + qg * QPB + q) * (OUTM * 3) + ql * 3;
    out[o + 0] = a0 * scale;
    out[o + 1] = a1 * scale;
    out[o + 2] = a2 * scale;
  }
}

// coords [B*N][3] -> x/y/z planes + float4 array.
__global__ void prep_kernel(const float* __restrict__ coords,
                            float* __restrict__ Xp, float* __restrict__ Yp,
                            float* __restrict__ Zp, float4* __restrict__ cpad) {
  int i = blockIdx.x * 256 + threadIdx.x;
  if (i < NQTOT) {
    float x = coords[3 * i + 0];
    float y = coords[3 * i + 1];
    float z = coords[3 * i + 2];
    Xp[i] = x; Yp[i] = y; Zp[i] = z;
    cpad[i] = make_float4(x, y, z, 0.f);
  }
}

extern "C" void kernel_launch(void* const* d_in, const int* in_sizes, int n_in,
                              void* d_out, int out_size, void* d_ws, size_t ws_size,
                              hipStream_t stream) {
  const float* coords = (const float*)d_in[0];
  const float* Wmat = (const float*)d_in[1];
  float* out = (float*)d_out;

  char* w = (char*)d_ws;
  float* Xp = (float*)(w);               // 128 KB
  float* Yp = (float*)(w + 131072);
  float* Zp = (float*)(w + 262144);
  float4* cpad = (float4*)(w + 393216);  // 512 KB

  prep_kernel<<<dim3((NQTOT + 255) / 256), dim3(256), 0, stream>>>(coords, Xp, Yp, Zp, cpad);
  se3_kernel<<<dim3(NBATCH, NPTS / QPB), dim3(TKNN), 0, stream>>>(Xp, Yp, Zp, cpad, Wmat, out);
}

// Round 7
// 211.835 us; speedup vs baseline: 1.1121x; 1.1121x over previous
//
#include <hip/hip_runtime.h>

typedef unsigned int u32;
typedef unsigned long long u64;
typedef float v2f __attribute__((ext_vector_type(2)));

#define NBATCH 8
#define NPTS   4096
#define NQTOT  (NBATCH * NPTS)   /* 32768 */
#define KNN    16
#define NBASIS 8
#define OUTM   64
#define NSPLIT 8
#define WIN    (NPTS / NSPLIT)   /* 512 candidates per window */
#define QPB    64
#define TKNN   (QPB * NSPLIT)    /* 512 threads = 8 waves */
#define GRP    8
#define BUFCAP 64
#define BUFSTR 65

// sentinel: d2 = +inf, idx = all-ones (sorts last)
#define SENT 0x7f800000ffffffffull

__device__ __forceinline__ void ce(u64& x, u64& y) {
  u64 a = x, b = y;
  bool sw = b < a;
  x = sw ? b : a;
  y = sw ? a : b;
}

// Batcher odd-even mergesort network (fully unrolled).
template <int N>
__device__ __forceinline__ void oems_sort(u64* a) {
#pragma unroll
  for (int p = 1; p < N; p <<= 1) {
#pragma unroll
    for (int k = p; k >= 1; k >>= 1) {
#pragma unroll
      for (int j = k & (p - 1); j + k < N; j += 2 * k) {
#pragma unroll
        for (int i = 0; i < k; ++i) {
          int lo = i + j, hi = i + j + k;
          if (hi < N && (lo / (2 * p)) == (hi / (2 * p)))
            ce(a[lo], a[hi]);
        }
      }
    }
  }
}

// t, a sorted asc -> t = smallest 16 of union, sorted asc.
__device__ __forceinline__ void merge16(u64 t[16], const u64 a[16]) {
  u64 m[16];
#pragma unroll
  for (int i = 0; i < 16; ++i) {
    u64 x = t[i], y = a[15 - i];
    m[i] = (x < y) ? x : y;
  }
#pragma unroll
  for (int k = 8; k >= 1; k >>= 1) {
#pragma unroll
    for (int i = 0; i < 16; ++i) {
      if ((i & k) == 0) ce(m[i], m[i | k]);
    }
  }
#pragma unroll
  for (int i = 0; i < 16; ++i) t[i] = m[i];
}

// Bit-exact d2 for a candidate pair: ((dx^2+dy^2)+dz^2), no FMA contraction.
// float2 ext-vector ops lower to v_pk_{add,mul}_f32 (IEEE-identical rounding;
// verified bit-exact vs reference in round 5).
__device__ __forceinline__ v2f d2pair(v2f cx, v2f cy, v2f cz, v2f qx, v2f qy,
                                      v2f qz) {
#pragma clang fp contract(off)
  v2f dx = cx - qx;
  v2f dy = cy - qy;
  v2f dz = cz - qz;
  v2f d2 = (dx * dx + dy * dy) + dz * dz;
  return d2;
}

// Fused kNN + tensor-product features (R4 funnel structure, upgraded).
// Block = 64 queries x 8 disjoint candidate windows (512 thr).
// Seed: each thread sorts its window's first 16 -> pre-sorted batches; owner
// merges 7 (merge-only, no sort) -> thr = 16th of 128 samples immediately.
// Phases double in size so E[appends/phase] ~= 16 constant; owner digests
// the shared per-query funnel at each phase end. Epilogue as before.
__global__ __launch_bounds__(TKNN, 6) void se3_kernel(
    const float* __restrict__ Xp, const float* __restrict__ Yp,
    const float* __restrict__ Zp, const float4* __restrict__ cpad,
    const float* __restrict__ Wmat, float* __restrict__ out) {
  __shared__ u64 sBuf[QPB * BUFSTR];  // 33.3 KB shared candidate funnel
  __shared__ u32 sCnt[QPB];
  __shared__ float sThr[QPB];
  __shared__ float sM[QPB * 25];      // M[8][3] per query, stride 25

  const int b = blockIdx.x;
  const int qg = blockIdx.y;
  const int tid = threadIdx.x;
  const int ql = tid & 63;
  const int sp = tid >> 6;  // window id, wave-uniform
  const int qi = qg * QPB + ql;
  const int base = b * NPTS;

  if (tid < QPB) sCnt[tid] = 0;

  // per-lane query coords (coalesced)
  const float qx = Xp[base + qi];
  const float qy = Yp[base + qi];
  const float qz = Zp[base + qi];
  const v2f qxx = {qx, qx}, qyy = {qy, qy}, qzz = {qz, qz};

  // wave-uniform candidate window -> scalar loads feeding packed math
  const int wbase = __builtin_amdgcn_readfirstlane(sp * WIN);
  const v2f* xs2 = (const v2f*)(Xp + base + wbase);
  const v2f* ys2 = (const v2f*)(Yp + base + wbase);
  const v2f* zs2 = (const v2f*)(Zp + base + wbase);
  const int sj = qi - wbase;  // self position inside window (may be OOR)

  // ---- Seed: every thread sorts its window's first 16 candidates ----
  u64 t16[16];
  {
    float cd[16];
#pragma unroll
    for (int p = 0; p < 8; ++p) {
      v2f d2 = d2pair(xs2[p], ys2[p], zs2[p], qxx, qyy, qzz);
      cd[2 * p + 0] = d2.x;
      cd[2 * p + 1] = d2.y;
    }
#pragma unroll
    for (int i = 0; i < 16; ++i) {
      u64 v = ((u64)__float_as_uint(cd[i]) << 32) | (u32)(wbase + i);
      t16[i] = (i == sj) ? SENT : v;
    }
    oems_sort<16>(t16);
  }

  // ---- Seed ingest: two publish rounds (BUFCAP = 4 batches of 16) ----
  // Round A: windows 1..4 publish pre-sorted lists; owner merges 4.
  if (sp >= 1 && sp <= 4) {
#pragma unroll
    for (int e = 0; e < 16; ++e) sBuf[ql * BUFSTR + (sp - 1) * 16 + e] = t16[e];
  }
  __syncthreads();
  if (sp == 0) {
#pragma unroll
    for (int s = 0; s < 4; ++s) {
      u64 a[16];
#pragma unroll
      for (int e = 0; e < 16; ++e) a[e] = sBuf[ql * BUFSTR + s * 16 + e];
      merge16(t16, a);
    }
  }
  __syncthreads();
  // Round B: windows 5..7 publish; owner merges 3, writes threshold.
  if (sp >= 5) {
#pragma unroll
    for (int e = 0; e < 16; ++e) sBuf[ql * BUFSTR + (sp - 5) * 16 + e] = t16[e];
  }
  __syncthreads();
  if (sp == 0) {
#pragma unroll
    for (int s = 0; s < 3; ++s) {
      u64 a[16];
#pragma unroll
      for (int e = 0; e < 16; ++e) a[e] = sBuf[ql * BUFSTR + s * 16 + e];
      merge16(t16, a);
    }
    sThr[ql] = __uint_as_float((u32)(t16[15] >> 32));
  }
  __syncthreads();
  float thr = sThr[ql];

  // self-exclusion mask precompute (avoids per-candidate j!=qi compare)
  const int selfgrp = (sj >= 0 && sj < WIN) ? (sj >> 3) : -1;
  const u32 selfbit = 1u << (sj & 7);

  // ---- Main scan: doubling phases, E[appends] ~= 16 per phase per query ----
#pragma unroll
  for (int ph = 0; ph < 5; ++ph) {
    const int cstart = 16 << ph;  // [16,32),[32,64),...,[256,512)
    const int cend = 32 << ph;
    for (int g = cstart; g < cend; g += GRP) {
      v2f d2p[4];
#pragma unroll
      for (int p = 0; p < 4; ++p)
        d2p[p] = d2pair(xs2[(g >> 1) + p], ys2[(g >> 1) + p],
                        zs2[(g >> 1) + p], qxx, qyy, qzz);
      u32 want = 0;
#pragma unroll
      for (int i = 0; i < GRP; ++i)
        want |= (d2p[i >> 1][i & 1] <= thr) ? (1u << i) : 0u;
      if ((g >> 3) == selfgrp) want &= ~selfbit;
      if (__any(want)) {
#pragma unroll
        for (int i = 0; i < GRP; ++i) {
          if (want & (1u << i)) {
            u32 slot = atomicAdd(&sCnt[ql], 1u);
            if (slot < BUFCAP)
              sBuf[ql * BUFSTR + slot] =
                  ((u64)__float_as_uint(d2p[i >> 1][i & 1]) << 32) |
                  (u32)(wbase + g + i);
          }
        }
      }
    }
    __syncthreads();
    if (sp == 0) {  // owner digests its query's funnel
      int n = (int)sCnt[ql];
      n = n < BUFCAP ? n : BUFCAP;
      for (int k = 0; __any(k < n); k += 16) {
        u64 a[16];
#pragma unroll
        for (int e = 0; e < 16; ++e)
          a[e] = (k + e < n) ? sBuf[ql * BUFSTR + k + e] : SENT;
        oems_sort<16>(a);
        merge16(t16, a);
      }
      sCnt[ql] = 0;
      sThr[ql] = __uint_as_float((u32)(t16[15] >> 32));
    }
    __syncthreads();
    thr = sThr[ql];
  }

  // ---- Epilogue phase 1 (owner wave): M[8][3] from exact top-16 ----
  if (sp == 0) {
    float M[24];
#pragma unroll
    for (int j = 0; j < 24; ++j) M[j] = 0.f;
#pragma unroll
    for (int chk = 0; chk < 4; ++chk) {
      float4 nc[4];
      float dd[4];
#pragma unroll
      for (int e = 0; e < 4; ++e) {
        u64 v = t16[chk * 4 + e];
        nc[e] = cpad[base + (int)(u32)v];  // independent gathers
        dd[e] = __uint_as_float((u32)(v >> 32));
      }
#pragma unroll
      for (int e = 0; e < 4; ++e) {
        float rx = nc[e].x - qx;  // sender - receiver
        float ry = nc[e].y - qy;
        float rz = nc[e].z - qz;
        float dist = sqrtf(dd[e]);
        float inv = 1.0f / (dist + 1e-8f);
        rx *= inv; ry *= inv; rz *= inv;
        float cut = fminf(dist * 0.1f, 1.0f);
        float g[NBASIS], s = 0.f;
#pragma unroll
        for (int v = 0; v < NBASIS; ++v) {
          float t = cut - (float)v * (1.0f / 7.0f);
          g[v] = __expf(-32.0f * t * t);  // sigma = 1/8 -> 1/(2s^2) = 32
          s += g[v];
        }
        float rs = 1.0f / s;
#pragma unroll
        for (int v = 0; v < NBASIS; ++v) {
          float rb = g[v] * rs;
          M[v * 3 + 0] = fmaf(rb, rx, M[v * 3 + 0]);
          M[v * 3 + 1] = fmaf(rb, ry, M[v * 3 + 1]);
          M[v * 3 + 2] = fmaf(rb, rz, M[v * 3 + 2]);
        }
      }
    }
#pragma unroll
    for (int j = 0; j < 24; ++j) sM[ql * 25 + j] = M[j];
  }
  __syncthreads();

  // ---- Epilogue phase 2 (all waves): out[q][w*3+m], lane w = ql ----
  float wreg[NBASIS];
#pragma unroll
  for (int v = 0; v < NBASIS; ++v) wreg[v] = Wmat[v * OUTM + ql];
  const float scale = 0.022097086912079608f;  // (1/sqrt(8)) / 16
#pragma unroll
  for (int i = 0; i < 8; ++i) {
    int q = sp * 8 + i;  // wave-uniform -> sM broadcasts
    const float* mq = sM + q * 25;
    float a0 = 0.f, a1 = 0.f, a2 = 0.f;
#pragma unroll
    for (int v = 0; v < NBASIS; ++v) {
      a0 = fmaf(wreg[v], mq[v * 3 + 0], a0);
      a1 = fmaf(wreg[v], mq[v * 3 + 1], a1);
      a2 = fmaf(wreg[v], mq[v * 3 + 2], a2);
    }
    size_t o = (size_t)(base + qg * QPB + q) * (OUTM * 3) + ql * 3;
    out[o + 0] = a0 * scale;
    out[o + 1] = a1 * scale;
    out[o + 2] = a2 * scale;
  }
}

// coords [B*N][3] -> x/y/z planes + float4 array.
__global__ void prep_kernel(const float* __restrict__ coords,
                            float* __restrict__ Xp, float* __restrict__ Yp,
                            float* __restrict__ Zp, float4* __restrict__ cpad) {
  int i = blockIdx.x * 256 + threadIdx.x;
  if (i < NQTOT) {
    float x = coords[3 * i + 0];
    float y = coords[3 * i + 1];
    float z = coords[3 * i + 2];
    Xp[i] = x; Yp[i] = y; Zp[i] = z;
    cpad[i] = make_float4(x, y, z, 0.f);
  }
}

extern "C" void kernel_launch(void* const* d_in, const int* in_sizes, int n_in,
                              void* d_out, int out_size, void* d_ws, size_t ws_size,
                              hipStream_t stream) {
  const float* coords = (const float*)d_in[0];
  const float* Wmat = (const float*)d_in[1];
  float* out = (float*)d_out;

  char* w = (char*)d_ws;
  float* Xp = (float*)(w);               // 128 KB
  float* Yp = (float*)(w + 131072);
  float* Zp = (float*)(w + 262144);
  float4* cpad = (float4*)(w + 393216);  // 512 KB

  prep_kernel<<<dim3((NQTOT + 255) / 256), dim3(256), 0, stream>>>(coords, Xp, Yp, Zp, cpad);
  se3_kernel<<<dim3(NBATCH, NPTS / QPB), dim3(TKNN), 0, stream>>>(Xp, Yp, Zp, cpad, Wmat, out);
}

// Round 8
// 183.590 us; speedup vs baseline: 1.2832x; 1.1538x over previous
//
#include <hip/hip_runtime.h>

typedef unsigned int u32;
typedef unsigned long long u64;
typedef float v2f __attribute__((ext_vector_type(2)));

#define NBATCH 8
#define NPTS   4096
#define NQTOT  (NBATCH * NPTS)   /* 32768 */
#define KNN    16
#define NBASIS 8
#define OUTM   64
#define NSPLIT 8
#define WIN    (NPTS / NSPLIT)   /* 512 candidates per window */
#define QPB    64
#define TKNN   (QPB * NSPLIT)    /* 512 threads = 8 waves */
#define GRP    8
#define BUFCAP 64
#define BUFSTR 65

// sentinel: d2 = +inf, idx = all-ones (sorts last)
#define SENT 0x7f800000ffffffffull

__device__ __forceinline__ void ce(u64& x, u64& y) {
  u64 a = x, b = y;
  bool sw = b < a;
  x = sw ? b : a;
  y = sw ? a : b;
}

// Batcher odd-even mergesort network (fully unrolled).
template <int N>
__device__ __forceinline__ void oems_sort(u64* a) {
#pragma unroll
  for (int p = 1; p < N; p <<= 1) {
#pragma unroll
    for (int k = p; k >= 1; k >>= 1) {
#pragma unroll
      for (int j = k & (p - 1); j + k < N; j += 2 * k) {
#pragma unroll
        for (int i = 0; i < k; ++i) {
          int lo = i + j, hi = i + j + k;
          if (hi < N && (lo / (2 * p)) == (hi / (2 * p)))
            ce(a[lo], a[hi]);
        }
      }
    }
  }
}

// t, a sorted asc -> t = smallest 16 of union, sorted asc.
__device__ __forceinline__ void merge16(u64 t[16], const u64 a[16]) {
  u64 m[16];
#pragma unroll
  for (int i = 0; i < 16; ++i) {
    u64 x = t[i], y = a[15 - i];
    m[i] = (x < y) ? x : y;
  }
#pragma unroll
  for (int k = 8; k >= 1; k >>= 1) {
#pragma unroll
    for (int i = 0; i < 16; ++i) {
      if ((i & k) == 0) ce(m[i], m[i | k]);
    }
  }
#pragma unroll
  for (int i = 0; i < 16; ++i) t[i] = m[i];
}

// Bit-exact d2 for a candidate pair: ((dx^2+dy^2)+dz^2), no FMA contraction.
// float2 ext-vector ops lower to v_pk_{add,mul}_f32 (IEEE-identical rounding;
// verified bit-exact vs reference in round 5/6).
__device__ __forceinline__ v2f d2pair(v2f cx, v2f cy, v2f cz, v2f qx, v2f qy,
                                      v2f qz) {
#pragma clang fp contract(off)
  v2f dx = cx - qx;
  v2f dy = cy - qy;
  v2f dz = cz - qz;
  v2f d2 = (dx * dx + dy * dy) + dz * dz;
  return d2;
}

// Fused kNN + tensor-product features (R4 funnel structure, upgraded).
// Block = 64 queries x 8 disjoint candidate windows (512 thr).
// Seed: each thread sorts its window's first 16 -> pre-sorted batches; owner
// merges 7 (merge-only, no sort) -> thr = 16th of 128 samples immediately.
// Phases double in size so E[appends/phase] ~= 16 constant; owner digests
// the shared per-query funnel at each phase end. Epilogue as before.
// launch_bounds min-waves = 4: VGPR budget ~128/wave. DO NOT raise to 6 —
// round 7 measured VGPR forced to 40, spilling t16 to scratch (+48 MB HBM).
__global__ __launch_bounds__(TKNN, 4) void se3_kernel(
    const float* __restrict__ Xp, const float* __restrict__ Yp,
    const float* __restrict__ Zp, const float4* __restrict__ cpad,
    const float* __restrict__ Wmat, float* __restrict__ out) {
  __shared__ u64 sBuf[QPB * BUFSTR];  // 33.3 KB shared candidate funnel
  __shared__ u32 sCnt[QPB];
  __shared__ float sThr[QPB];
  __shared__ float sM[QPB * 25];      // M[8][3] per query, stride 25

  const int b = blockIdx.x;
  const int qg = blockIdx.y;
  const int tid = threadIdx.x;
  const int ql = tid & 63;
  const int sp = tid >> 6;  // window id, wave-uniform
  const int qi = qg * QPB + ql;
  const int base = b * NPTS;

  if (tid < QPB) sCnt[tid] = 0;

  // per-lane query coords (coalesced)
  const float qx = Xp[base + qi];
  const float qy = Yp[base + qi];
  const float qz = Zp[base + qi];
  const v2f qxx = {qx, qx}, qyy = {qy, qy}, qzz = {qz, qz};

  // wave-uniform candidate window -> scalar loads feeding packed math
  const int wbase = __builtin_amdgcn_readfirstlane(sp * WIN);
  const v2f* xs2 = (const v2f*)(Xp + base + wbase);
  const v2f* ys2 = (const v2f*)(Yp + base + wbase);
  const v2f* zs2 = (const v2f*)(Zp + base + wbase);
  const int sj = qi - wbase;  // self position inside window (may be OOR)

  // ---- Seed: every thread sorts its window's first 16 candidates ----
  u64 t16[16];
  {
    float cd[16];
#pragma unroll
    for (int p = 0; p < 8; ++p) {
      v2f d2 = d2pair(xs2[p], ys2[p], zs2[p], qxx, qyy, qzz);
      cd[2 * p + 0] = d2.x;
      cd[2 * p + 1] = d2.y;
    }
#pragma unroll
    for (int i = 0; i < 16; ++i) {
      u64 v = ((u64)__float_as_uint(cd[i]) << 32) | (u32)(wbase + i);
      t16[i] = (i == sj) ? SENT : v;
    }
    oems_sort<16>(t16);
  }

  // ---- Seed ingest: two publish rounds (BUFCAP = 4 batches of 16) ----
  // Round A: windows 1..4 publish pre-sorted lists; owner merges 4.
  if (sp >= 1 && sp <= 4) {
#pragma unroll
    for (int e = 0; e < 16; ++e) sBuf[ql * BUFSTR + (sp - 1) * 16 + e] = t16[e];
  }
  __syncthreads();
  if (sp == 0) {
#pragma unroll
    for (int s = 0; s < 4; ++s) {
      u64 a[16];
#pragma unroll
      for (int e = 0; e < 16; ++e) a[e] = sBuf[ql * BUFSTR + s * 16 + e];
      merge16(t16, a);
    }
  }
  __syncthreads();
  // Round B: windows 5..7 publish; owner merges 3, writes threshold.
  if (sp >= 5) {
#pragma unroll
    for (int e = 0; e < 16; ++e) sBuf[ql * BUFSTR + (sp - 5) * 16 + e] = t16[e];
  }
  __syncthreads();
  if (sp == 0) {
#pragma unroll
    for (int s = 0; s < 3; ++s) {
      u64 a[16];
#pragma unroll
      for (int e = 0; e < 16; ++e) a[e] = sBuf[ql * BUFSTR + s * 16 + e];
      merge16(t16, a);
    }
    sThr[ql] = __uint_as_float((u32)(t16[15] >> 32));
  }
  __syncthreads();
  float thr = sThr[ql];

  // self-exclusion mask precompute (avoids per-candidate j!=qi compare)
  const int selfgrp = (sj >= 0 && sj < WIN) ? (sj >> 3) : -1;
  const u32 selfbit = 1u << (sj & 7);

  // ---- Main scan: doubling phases, E[appends] ~= 16 per phase per query ----
#pragma unroll
  for (int ph = 0; ph < 5; ++ph) {
    const int cstart = 16 << ph;  // [16,32),[32,64),...,[256,512)
    const int cend = 32 << ph;
    for (int g = cstart; g < cend; g += GRP) {
      v2f d2p[4];
#pragma unroll
      for (int p = 0; p < 4; ++p)
        d2p[p] = d2pair(xs2[(g >> 1) + p], ys2[(g >> 1) + p],
                        zs2[(g >> 1) + p], qxx, qyy, qzz);
      u32 want = 0;
#pragma unroll
      for (int i = 0; i < GRP; ++i)
        want |= (d2p[i >> 1][i & 1] <= thr) ? (1u << i) : 0u;
      if ((g >> 3) == selfgrp) want &= ~selfbit;
      if (__any(want)) {
#pragma unroll
        for (int i = 0; i < GRP; ++i) {
          if (want & (1u << i)) {
            u32 slot = atomicAdd(&sCnt[ql], 1u);
            if (slot < BUFCAP)
              sBuf[ql * BUFSTR + slot] =
                  ((u64)__float_as_uint(d2p[i >> 1][i & 1]) << 32) |
                  (u32)(wbase + g + i);
          }
        }
      }
    }
    __syncthreads();
    if (sp == 0) {  // owner digests its query's funnel
      int n = (int)sCnt[ql];
      n = n < BUFCAP ? n : BUFCAP;
      for (int k = 0; __any(k < n); k += 16) {
        u64 a[16];
#pragma unroll
        for (int e = 0; e < 16; ++e)
          a[e] = (k + e < n) ? sBuf[ql * BUFSTR + k + e] : SENT;
        oems_sort<16>(a);
        merge16(t16, a);
      }
      sCnt[ql] = 0;
      sThr[ql] = __uint_as_float((u32)(t16[15] >> 32));
    }
    __syncthreads();
    thr = sThr[ql];
  }

  // ---- Epilogue phase 1 (owner wave): M[8][3] from exact top-16 ----
  if (sp == 0) {
    float M[24];
#pragma unroll
    for (int j = 0; j < 24; ++j) M[j] = 0.f;
#pragma unroll
    for (int chk = 0; chk < 4; ++chk) {
      float4 nc[4];
      float dd[4];
#pragma unroll
      for (int e = 0; e < 4; ++e) {
        u64 v = t16[chk * 4 + e];
        nc[e] = cpad[base + (int)(u32)v];  // independent gathers
        dd[e] = __uint_as_float((u32)(v >> 32));
      }
#pragma unroll
      for (int e = 0; e < 4; ++e) {
        float rx = nc[e].x - qx;  // sender - receiver
        float ry = nc[e].y - qy;
        float rz = nc[e].z - qz;
        float dist = sqrtf(dd[e]);
        float inv = 1.0f / (dist + 1e-8f);
        rx *= inv; ry *= inv; rz *= inv;
        float cut = fminf(dist * 0.1f, 1.0f);
        float g[NBASIS], s = 0.f;
#pragma unroll
        for (int v = 0; v < NBASIS; ++v) {
          float t = cut - (float)v * (1.0f / 7.0f);
          g[v] = __expf(-32.0f * t * t);  // sigma = 1/8 -> 1/(2s^2) = 32
          s += g[v];
        }
        float rs = 1.0f / s;
#pragma unroll
        for (int v = 0; v < NBASIS; ++v) {
          float rb = g[v] * rs;
          M[v * 3 + 0] = fmaf(rb, rx, M[v * 3 + 0]);
          M[v * 3 + 1] = fmaf(rb, ry, M[v * 3 + 1]);
          M[v * 3 + 2] = fmaf(rb, rz, M[v * 3 + 2]);
        }
      }
    }
#pragma unroll
    for (int j = 0; j < 24; ++j) sM[ql * 25 + j] = M[j];
  }
  __syncthreads();

  // ---- Epilogue phase 2 (all waves): out[q][w*3+m], lane w = ql ----
  float wreg[NBASIS];
#pragma unroll
  for (int v = 0; v < NBASIS; ++v) wreg[v] = Wmat[v * OUTM + ql];
  const float scale = 0.022097086912079608f;  // (1/sqrt(8)) / 16
#pragma unroll
  for (int i = 0; i < 8; ++i) {
    int q = sp * 8 + i;  // wave-uniform -> sM broadcasts
    const float* mq = sM + q * 25;
    float a0 = 0.f, a1 = 0.f, a2 = 0.f;
#pragma unroll
    for (int v = 0; v < NBASIS; ++v) {
      a0 = fmaf(wreg[v], mq[v * 3 + 0], a0);
      a1 = fmaf(wreg[v], mq[v * 3 + 1], a1);
      a2 = fmaf(wreg[v], mq[v * 3 + 2], a2);
    }
    size_t o = (size_t)(base + qg * QPB + q) * (OUTM * 3) + ql * 3;
    out[o + 0] = a0 * scale;
    out[o + 1] = a1 * scale;
    out[o + 2] = a2 * scale;
  }
}

// coords [B*N][3] -> x/y/z planes + float4 array.
__global__ void prep_kernel(const float* __restrict__ coords,
                            float* __restrict__ Xp, float* __restrict__ Yp,
                            float* __restrict__ Zp, float4* __restrict__ cpad) {
  int i = blockIdx.x * 256 + threadIdx.x;
  if (i < NQTOT) {
    float x = coords[3 * i + 0];
    float y = coords[3 * i + 1];
    float z = coords[3 * i + 2];
    Xp[i] = x; Yp[i] = y; Zp[i] = z;
    cpad[i] = make_float4(x, y, z, 0.f);
  }
}

extern "C" void kernel_launch(void* const* d_in, const int* in_sizes, int n_in,
                              void* d_out, int out_size, void* d_ws, size_t ws_size,
                              hipStream_t stream) {
  const float* coords = (const float*)d_in[0];
  const float* Wmat = (const float*)d_in[1];
  float* out = (float*)d_out;

  char* w = (char*)d_ws;
  float* Xp = (float*)(w);               // 128 KB
  float* Yp = (float*)(w + 131072);
  float* Zp = (float*)(w + 262144);
  float4* cpad = (float4*)(w + 393216);  // 512 KB

  prep_kernel<<<dim3((NQTOT + 255) / 256), dim3(256), 0, stream>>>(coords, Xp, Yp, Zp, cpad);
  se3_kernel<<<dim3(NBATCH, NPTS / QPB), dim3(TKNN), 0, stream>>>(Xp, Yp, Zp, cpad, Wmat, out);
}

// Round 9
// 179.429 us; speedup vs baseline: 1.3130x; 1.0232x over previous
//
#include <hip/hip_runtime.h>

typedef unsigned int u32;
typedef unsigned long long u64;
typedef float v2f __attribute__((ext_vector_type(2)));

#define NBATCH 8
#define NPTS   4096
#define NQTOT  (NBATCH * NPTS)   /* 32768 */
#define KNN    16
#define NBASIS 8
#define OUTM   64
#define NSPLIT 8
#define WIN    (NPTS / NSPLIT)   /* 512 candidates per window */
#define QPB    64
#define TKNN   (QPB * NSPLIT)    /* 512 threads = 8 waves */
#define GRP    8
#define BUFCAP 64
/* per-query LDS row: 64 funnel slots + 16 t16 slots + 1 pad (odd stride) */
#define ROWSTR 81
#define TOFF   64

// sentinel: d2 = +inf, idx = all-ones (sorts last)
#define SENT 0x7f800000ffffffffull

__device__ __forceinline__ void ce(u64& x, u64& y) {
  u64 a = x, b = y;
  bool sw = b < a;
  x = sw ? b : a;
  y = sw ? a : b;
}

// Batcher odd-even mergesort network (fully unrolled).
template <int N>
__device__ __forceinline__ void oems_sort(u64* a) {
#pragma unroll
  for (int p = 1; p < N; p <<= 1) {
#pragma unroll
    for (int k = p; k >= 1; k >>= 1) {
#pragma unroll
      for (int j = k & (p - 1); j + k < N; j += 2 * k) {
#pragma unroll
        for (int i = 0; i < k; ++i) {
          int lo = i + j, hi = i + j + k;
          if (hi < N && (lo / (2 * p)) == (hi / (2 * p)))
            ce(a[lo], a[hi]);
        }
      }
    }
  }
}

// t, a sorted asc -> t = smallest 16 of union, sorted asc.
__device__ __forceinline__ void merge16(u64 t[16], const u64 a[16]) {
  u64 m[16];
#pragma unroll
  for (int i = 0; i < 16; ++i) {
    u64 x = t[i], y = a[15 - i];
    m[i] = (x < y) ? x : y;
  }
#pragma unroll
  for (int k = 8; k >= 1; k >>= 1) {
#pragma unroll
    for (int i = 0; i < 16; ++i) {
      if ((i & k) == 0) ce(m[i], m[i | k]);
    }
  }
#pragma unroll
  for (int i = 0; i < 16; ++i) t[i] = m[i];
}

// Bit-exact d2 for a candidate pair: ((dx^2+dy^2)+dz^2), no FMA contraction.
// float2 ext-vector ops lower to v_pk_{add,mul}_f32 (IEEE-identical rounding;
// verified bit-exact vs reference rounds 5-8).
__device__ __forceinline__ v2f d2pair(v2f cx, v2f cy, v2f cz, v2f qx, v2f qy,
                                      v2f qz) {
#pragma clang fp contract(off)
  v2f dx = cx - qx;
  v2f dy = cy - qy;
  v2f dz = cz - qz;
  v2f d2 = (dx * dx + dy * dy) + dz * dz;
  return d2;
}

// Fused kNN + tensor-product features, de-serialized funnel version.
// Block = 64 queries x 8 disjoint windows. Running top-16 per query lives in
// the query's LDS row (sT); phase digests rotate across waves; epilogue-M is
// distributed over waves 0-3 (one (query,quarter) per thread) with LDS
// reduction. NO __launch_bounds__ min-waves: rounds 7/8 measured forced VGPR
// (40/64) -> scratch spills (+48/+11 MB HBM). Let the allocator breathe.
__global__ __launch_bounds__(TKNN) void se3_kernel(
    const float* __restrict__ Xp, const float* __restrict__ Yp,
    const float* __restrict__ Zp, const float4* __restrict__ cpad,
    const float* __restrict__ Wmat, float* __restrict__ out) {
  __shared__ u64 sBuf[QPB * ROWSTR];  // 41.5 KB: funnel + t16 per query row
  __shared__ u32 sCnt[QPB];
  __shared__ float sThr[QPB];
  __shared__ float sM[QPB * 25];      // reduced M[8][3], stride 25

  const int b = blockIdx.x;
  const int qg = blockIdx.y;
  const int tid = threadIdx.x;
  const int ql = tid & 63;
  const int sp = tid >> 6;  // window id, wave-uniform
  const int qi = qg * QPB + ql;
  const int base = b * NPTS;

  if (tid < QPB) sCnt[tid] = 0;

  // per-lane query coords (coalesced)
  const float qx = Xp[base + qi];
  const float qy = Yp[base + qi];
  const float qz = Zp[base + qi];
  const v2f qxx = {qx, qx}, qyy = {qy, qy}, qzz = {qz, qz};

  // wave-uniform candidate window -> scalar loads feeding packed math
  const int wbase = __builtin_amdgcn_readfirstlane(sp * WIN);
  const v2f* xs2 = (const v2f*)(Xp + base + wbase);
  const v2f* ys2 = (const v2f*)(Yp + base + wbase);
  const v2f* zs2 = (const v2f*)(Zp + base + wbase);
  const int sj = qi - wbase;  // self position inside window (may be OOR)

  // ---- Seed: every thread sorts its window's first 16 candidates ----
  {
    u64 s16[16];
    float cd[16];
#pragma unroll
    for (int p = 0; p < 8; ++p) {
      v2f d2 = d2pair(xs2[p], ys2[p], zs2[p], qxx, qyy, qzz);
      cd[2 * p + 0] = d2.x;
      cd[2 * p + 1] = d2.y;
    }
#pragma unroll
    for (int i = 0; i < 16; ++i) {
      u64 v = ((u64)__float_as_uint(cd[i]) << 32) | (u32)(wbase + i);
      s16[i] = (i == sj) ? SENT : v;
    }
    oems_sort<16>(s16);

    // Round A: waves 1..4 publish pre-sorted lists into funnel slots.
    if (sp >= 1 && sp <= 4) {
#pragma unroll
      for (int e = 0; e < 16; ++e)
        sBuf[ql * ROWSTR + (sp - 1) * 16 + e] = s16[e];
    }
    __syncthreads();
    if (sp == 0) {
      u64 t16[16];
#pragma unroll
      for (int e = 0; e < 16; ++e) t16[e] = s16[e];
#pragma unroll
      for (int s = 0; s < 4; ++s) {
        u64 a[16];
#pragma unroll
        for (int e = 0; e < 16; ++e) a[e] = sBuf[ql * ROWSTR + s * 16 + e];
        merge16(t16, a);
      }
      // stash partial in sT while round B publishes
#pragma unroll
      for (int e = 0; e < 16; ++e) sBuf[ql * ROWSTR + TOFF + e] = t16[e];
    }
    __syncthreads();
    // Round B: waves 5..7 publish.
    if (sp >= 5) {
#pragma unroll
      for (int e = 0; e < 16; ++e)
        sBuf[ql * ROWSTR + (sp - 5) * 16 + e] = s16[e];
    }
    __syncthreads();
    if (sp == 0) {
      u64 t16[16];
#pragma unroll
      for (int e = 0; e < 16; ++e) t16[e] = sBuf[ql * ROWSTR + TOFF + e];
#pragma unroll
      for (int s = 0; s < 3; ++s) {
        u64 a[16];
#pragma unroll
        for (int e = 0; e < 16; ++e) a[e] = sBuf[ql * ROWSTR + s * 16 + e];
        merge16(t16, a);
      }
#pragma unroll
      for (int e = 0; e < 16; ++e) sBuf[ql * ROWSTR + TOFF + e] = t16[e];
      sThr[ql] = __uint_as_float((u32)(t16[15] >> 32));
    }
    __syncthreads();
  }
  float thr = sThr[ql];

  // self-exclusion mask precompute (avoids per-candidate j!=qi compare)
  const int selfgrp = (sj >= 0 && sj < WIN) ? (sj >> 3) : -1;
  const u32 selfbit = 1u << (sj & 7);

  // ---- Main scan: doubling phases; digest wave rotates (1..5) ----
#pragma unroll
  for (int ph = 0; ph < 5; ++ph) {
    const int cstart = 16 << ph;  // [16,32),[32,64),...,[256,512)
    const int cend = 32 << ph;
    for (int g = cstart; g < cend; g += GRP) {
      v2f d2p[4];
#pragma unroll
      for (int p = 0; p < 4; ++p)
        d2p[p] = d2pair(xs2[(g >> 1) + p], ys2[(g >> 1) + p],
                        zs2[(g >> 1) + p], qxx, qyy, qzz);
      u32 want = 0;
#pragma unroll
      for (int i = 0; i < GRP; ++i)
        want |= (d2p[i >> 1][i & 1] <= thr) ? (1u << i) : 0u;
      if ((g >> 3) == selfgrp) want &= ~selfbit;
      if (__any(want)) {
#pragma unroll
        for (int i = 0; i < GRP; ++i) {
          if (want & (1u << i)) {
            u32 slot = atomicAdd(&sCnt[ql], 1u);
            if (slot < BUFCAP)
              sBuf[ql * ROWSTR + slot] =
                  ((u64)__float_as_uint(d2p[i >> 1][i & 1]) << 32) |
                  (u32)(wbase + g + i);
          }
        }
      }
    }
    __syncthreads();
    if (sp == ph + 1) {  // rotating digest wave (1..5)
      int n = (int)sCnt[ql];
      n = n < BUFCAP ? n : BUFCAP;
      if (__any(n > 0)) {
        u64 t16[16];
#pragma unroll
        for (int e = 0; e < 16; ++e) t16[e] = sBuf[ql * ROWSTR + TOFF + e];
        for (int k = 0; __any(k < n); k += 16) {
          u64 a[16];
#pragma unroll
          for (int e = 0; e < 16; ++e)
            a[e] = (k + e < n) ? sBuf[ql * ROWSTR + k + e] : SENT;
          oems_sort<16>(a);
          merge16(t16, a);
        }
#pragma unroll
        for (int e = 0; e < 16; ++e) sBuf[ql * ROWSTR + TOFF + e] = t16[e];
        sThr[ql] = __uint_as_float((u32)(t16[15] >> 32));
      }
      sCnt[ql] = 0;
    }
    __syncthreads();
    thr = sThr[ql];
  }

  // ---- Epilogue phase 1 (waves 0-3): partial M over 4 neighbors each ----
  // Thread (q = tid&63, quarter k = tid>>6) -> partials into dead funnel
  // floats [k*25, k*25+24) of row q (< float offset 100; sT starts at 128).
  if (sp < 4) {
    const int k = sp;
    u64 pv[4];
#pragma unroll
    for (int e = 0; e < 4; ++e)
      pv[e] = sBuf[ql * ROWSTR + TOFF + k * 4 + e];
    float4 nc[4];
    float dd[4];
#pragma unroll
    for (int e = 0; e < 4; ++e) {
      nc[e] = cpad[base + (int)(u32)pv[e]];  // independent gathers
      dd[e] = __uint_as_float((u32)(pv[e] >> 32));
    }
    float M[24];
#pragma unroll
    for (int j = 0; j < 24; ++j) M[j] = 0.f;
#pragma unroll
    for (int e = 0; e < 4; ++e) {
      float rx = nc[e].x - qx;  // sender - receiver
      float ry = nc[e].y - qy;
      float rz = nc[e].z - qz;
      float dist = sqrtf(dd[e]);
      float inv = 1.0f / (dist + 1e-8f);
      rx *= inv; ry *= inv; rz *= inv;
      float cut = fminf(dist * 0.1f, 1.0f);
      float g[NBASIS], s = 0.f;
#pragma unroll
      for (int v = 0; v < NBASIS; ++v) {
        float t = cut - (float)v * (1.0f / 7.0f);
        g[v] = __expf(-32.0f * t * t);  // sigma = 1/8 -> 1/(2s^2) = 32
        s += g[v];
      }
      float rs = 1.0f / s;
#pragma unroll
      for (int v = 0; v < NBASIS; ++v) {
        float rb = g[v] * rs;
        M[v * 3 + 0] = fmaf(rb, rx, M[v * 3 + 0]);
        M[v * 3 + 1] = fmaf(rb, ry, M[v * 3 + 1]);
        M[v * 3 + 2] = fmaf(rb, rz, M[v * 3 + 2]);
      }
    }
    float* fp = (float*)(sBuf + ql * ROWSTR);
#pragma unroll
    for (int c = 0; c < 24; ++c) fp[k * 25 + c] = M[c];
  }
  __syncthreads();

  // ---- Reduce partials: thread (q = ql, comps sp*3..sp*3+2) ----
  {
    const float* fp = (const float*)(sBuf + ql * ROWSTR);
#pragma unroll
    for (int j0 = 0; j0 < 3; ++j0) {
      int j = sp * 3 + j0;
      float s = fp[0 * 25 + j] + fp[1 * 25 + j] + fp[2 * 25 + j] +
                fp[3 * 25 + j];
      sM[ql * 25 + j] = s;
    }
  }
  __syncthreads();

  // ---- Epilogue phase 2 (all waves): out[q][w*3+m], lane w = ql ----
  float wreg[NBASIS];
#pragma unroll
  for (int v = 0; v < NBASIS; ++v) wreg[v] = Wmat[v * OUTM + ql];
  const float scale = 0.022097086912079608f;  // (1/sqrt(8)) / 16
#pragma unroll
  for (int i = 0; i < 8; ++i) {
    int q = sp * 8 + i;  // wave-uniform -> sM broadcasts
    const float* mq = sM + q * 25;
    float a0 = 0.f, a1 = 0.f, a2 = 0.f;
#pragma unroll
    for (int v = 0; v < NBASIS; ++v) {
      a0 = fmaf(wreg[v], mq[v * 3 + 0], a0);
      a1 = fmaf(wreg[v], mq[v * 3 + 1], a1);
      a2 = fmaf(wreg[v], mq[v * 3 + 2], a2);
    }
    size_t o = (size_t)(base + qg * QPB + q) * (OUTM * 3) + ql * 3;
    out[o + 0] = a0 * scale;
    out[o + 1] = a1 * scale;
    out[o + 2] = a2 * scale;
  }
}

// coords [B*N][3] -> x/y/z planes + float4 array.
__global__ void prep_kernel(const float* __restrict__ coords,
                            float* __restrict__ Xp, float* __restrict__ Yp,
                            float* __restrict__ Zp, float4* __restrict__ cpad) {
  int i = blockIdx.x * 256 + threadIdx.x;
  if (i < NQTOT) {
    float x = coords[3 * i + 0];
    float y = coords[3 * i + 1];
    float z = coords[3 * i + 2];
    Xp[i] = x; Yp[i] = y; Zp[i] = z;
    cpad[i] = make_float4(x, y, z, 0.f);
  }
}

extern "C" void kernel_launch(void* const* d_in, const int* in_sizes, int n_in,
                              void* d_out, int out_size, void* d_ws, size_t ws_size,
                              hipStream_t stream) {
  const float* coords = (const float*)d_in[0];
  const float* Wmat = (const float*)d_in[1];
  float* out = (float*)d_out;

  char* w = (char*)d_ws;
  float* Xp = (float*)(w);               // 128 KB
  float* Yp = (float*)(w + 131072);
  float* Zp = (float*)(w + 262144);
  float4* cpad = (float4*)(w + 393216);  // 512 KB

  prep_kernel<<<dim3((NQTOT + 255) / 256), dim3(256), 0, stream>>>(coords, Xp, Yp, Zp, cpad);
  se3_kernel<<<dim3(NBATCH, NPTS / QPB), dim3(TKNN), 0, stream>>>(Xp, Yp, Zp, cpad, Wmat, out);
}